// Round 2
// baseline (214.249 us; speedup 1.0000x reference)
//
#include <hip/hip_runtime.h>

// Problem constants
#define HB 1024   // NUM_BASIC (GEMM K)
#define HM 8192   // NUM_MIXED (GEMM M)
#define NR 735    // 105*7 actual GEMM N
#define NPAD 768  // padded N
#define NOUT 57   // output is (HM, 57, 57)

// Fused kernel tiling
#define FBM 32           // j-rows per block -> 256 blocks = 1/CU
#define FBK 32           // k per step -> 32 steps
#define NCHUNK 50        // 2 A-chunks + 48 B-chunks of 1KB per K-step
#define YLSTRIDE 772     // fp32 Yl stride (772 mod 32 == 4: clean 2-way banks)

// smem layout (bytes):
//  phase 1: As[p] @ p*2048 (2x2KB)  Bs[p] @ 4096 + p*49152 (2x48KB) -> 102400
//  phase 2: Yl @ 0 (32*772*4 = 98816)  ddl @ 98816 (32*57*4 = 7296) -> 106112
#define SMEM_BYTES 106112

typedef __attribute__((ext_vector_type(8))) _Float16 half8;
typedef __attribute__((ext_vector_type(4))) _Float16 half4v;
typedef __attribute__((ext_vector_type(4))) float floatx4;

// ---------------------------------------------------------------------------
// Kernel 1 (merged preps):
//  blocks [0, NPAD):        x2[r][h] = relu(te[h,t]*mat[h,n,m]) fp16,
//                           rows >= NR zeroed, K(h)-contiguous. r=(t*7+m)*7+n
//  blocks [NPAD, NPAD+8192): W fp32 -> fp16
// ---------------------------------------------------------------------------
__global__ __launch_bounds__(256) void prep_kernel(
    const float* __restrict__ mat, const float* __restrict__ tex,
    const float4* __restrict__ W,
    _Float16* __restrict__ Xh, half4v* __restrict__ Wh) {
  const int blk = blockIdx.x;
  if (blk < NPAD) {
    const int r = blk;
    const int n = r % 7;
    const int tm = r / 7;
    const int m = tm % 7;
    const int t = tm / 7;
#pragma unroll
    for (int i = 0; i < 4; ++i) {
      const int h = i * 256 + threadIdx.x;
      float v = 0.f;
      if (r < NR) {
        const float mv = mat[h * 49 + n * 7 + m];
        const float te = 1.f / (1.f + expf(-tex[h * 15 + t])) + 1.f;
        v = te * mv;
        v = v > 0.f ? v : 0.f;  // relu
      }
      Xh[r * HB + h] = (_Float16)v;
    }
  } else {
    const int idx = (blk - NPAD) * 256 + threadIdx.x;
    const float4 v = W[idx];
    half4v h;
    h.x = (_Float16)v.x;
    h.y = (_Float16)v.y;
    h.z = (_Float16)v.z;
    h.w = (_Float16)v.w;
    Wh[idx] = h;
  }
}

// ---------------------------------------------------------------------------
// Kernel 2: fused GEMM + normalize epilogue. One block owns FBM=32 full rows:
//   y[j][r] = relu(sum_h Wh[j][h]*Xh[r][h] + b[j])   (r = 0..767, in LDS)
//   dd[j][r] = rsqrt(max(1, rowsum_r))
//   out[j][r][q] = dd[r]*mixed[r][q]*dd[q]           (57x57, float4 stores)
// No Y intermediate in HBM (-50.4 MB round trip, -1 launch).
// GEMM: per K-step stage A 2KB + full B-slab 48KB (Xh L2-resident),
// 2-phase dbuf, 8 waves each 32x96 via 2x6 grid of 16x16x32 f16 MFMAs.
// ---------------------------------------------------------------------------
#define STAGE(pp, k0)                                                          \
  do {                                                                         \
    _Pragma("unroll")                                                          \
    for (int t_ = 0; t_ < 7; ++t_) {                                           \
      const int c_ = wave + t_ * 8;                                            \
      if (c_ < NCHUNK) {                                                       \
        const bool isA_ = (c_ < 2);                                            \
        const int row_ = (isA_ ? c_ : (c_ - 2)) * 16 + srow;                   \
        const _Float16* gsrc_ =                                                \
            isA_ ? (A + abase + (size_t)row_ * HB + (k0) + skh)                \
                 : (B + (size_t)row_ * HB + (k0) + skh);                       \
        char* ldst_ = isA_ ? (smem + (pp)*2048 + c_ * 1024)                    \
                           : (smem + 4096 + (pp)*49152 + (c_ - 2) * 1024);     \
        __builtin_amdgcn_global_load_lds(                                      \
            (const __attribute__((address_space(1))) void*)gsrc_,              \
            (__attribute__((address_space(3))) void*)ldst_, 16, 0, 0);         \
      }                                                                        \
    }                                                                          \
  } while (0)

__global__ __launch_bounds__(512) void fused_kernel(
    const _Float16* __restrict__ A,  // Wh [8192][1024]
    const _Float16* __restrict__ B,  // Xh [768][1024]
    const float* __restrict__ bias,  // [8192]
    float* __restrict__ out) {       // [8192][57*57]
  __shared__ __align__(16) char smem[SMEM_BYTES];

  const int tid = threadIdx.x;
  const int lane = tid & 63;
  const int wave = tid >> 6;  // 0..7
  const int blk = blockIdx.x;

  // staging: chunk c = 16 rows x 32 k (1KB); lane l covers bytes c*1024+l*16
  // -> row = c*16 + l/4, k-half offset = (l&3)*8 halfs
  const int srow = lane >> 2;
  const int skh = (lane & 3) * 8;
  const size_t abase = (size_t)(blk * FBM) * HB;

  // MFMA fragment indexing
  const int mrow = lane & 15;
  const int quad = lane >> 4;

  floatx4 acc[2][6] = {};

  STAGE(0, 0);
  __syncthreads();  // tile 0 visible

  int p = 0;
  for (int k0 = 0; k0 < HB; k0 += FBK) {
    if (k0 + FBK < HB) STAGE(p ^ 1, k0 + FBK);  // prefetch pre-compute

    const _Float16* Asp = (const _Float16*)(smem + p * 2048);
    const _Float16* Bsp = (const _Float16*)(smem + 4096 + p * 49152);
    half8 af[2], bf[6];
#pragma unroll
    for (int i = 0; i < 2; ++i)
      af[i] = *(const half8*)(Asp + (i * 16 + mrow) * FBK + quad * 8);
#pragma unroll
    for (int j = 0; j < 6; ++j)
      bf[j] = *(const half8*)(Bsp + (wave * 96 + j * 16 + mrow) * FBK + quad * 8);
#pragma unroll
    for (int i = 0; i < 2; ++i)
#pragma unroll
      for (int j = 0; j < 6; ++j)
        acc[i][j] =
            __builtin_amdgcn_mfma_f32_16x16x32_f16(af[i], bf[j], acc[i][j], 0, 0, 0);

    __syncthreads();  // drains vmcnt: prefetch landed; all waves done with p
    p ^= 1;
  }

  // ---- epilogue phase 1: acc (+bias, relu) -> Yl in LDS (aliases staging) --
  float* Yl = (float*)smem;
  float* ddl = (float*)(smem + 98816);
#pragma unroll
  for (int i = 0; i < 2; ++i) {
#pragma unroll
    for (int jf = 0; jf < 6; ++jf) {
#pragma unroll
      for (int reg = 0; reg < 4; ++reg) {
        const int jrow = i * 16 + quad * 4 + reg;        // 0..31
        const int col = wave * 96 + jf * 16 + mrow;      // 0..767
        float v = acc[i][jf][reg] + bias[blk * FBM + jrow];
        Yl[jrow * YLSTRIDE + col] = v > 0.f ? v : 0.f;
      }
    }
  }
  __syncthreads();

  // ---- epilogue phase 2: rowsums -> dd. 1824 (j,r) pairs over 512 threads --
  for (int pr = tid; pr < FBM * NOUT; pr += 512) {
    const int jj = pr / NOUT;
    const int r = pr % NOUT;
    float s;
    if (r == 0) {
      s = 9.f;
    } else {
      const int c = (r - 1) / 7;
      const int n = (r - 1) % 7;
      const int base = 7 * (7 - c);  // starts[c]
      s = (n == 6) ? 1.f : 0.f;      // mixed[r][0]
      const float* lyj = Yl + jj * YLSTRIDE;
#pragma unroll
      for (int q = 0; q < 56; ++q) s += lyj[(base + q) * 7 + n];
    }
    s = s < 1.f ? 1.f : s;  // clip(.,1,None)
    ddl[jj * NOUT + r] = rsqrtf(s);
  }
  __syncthreads();

  // ---- epilogue phase 3: write out. Block region = 32*3249 floats =
  // 25992 float4, contiguous & 16B-aligned (415872 B) -> full coalescing. ---
  float* ob = out + (size_t)blk * FBM * (NOUT * NOUT);
  for (int v4 = tid; v4 < FBM * NOUT * NOUT / 4; v4 += 512) {
    float4 o;
#pragma unroll
    for (int e = 0; e < 4; ++e) {
      const int f = v4 * 4 + e;
      const int jj = f / (NOUT * NOUT);
      const int rem = f - jj * (NOUT * NOUT);
      const int r = rem / NOUT;
      const int q = rem - r * NOUT;
      const float* lyj = Yl + jj * YLSTRIDE;
      const float* dj = ddl + jj * NOUT;
      float val;
      if (r == 0) {
        val = (q % 7 == 0) ? dj[0] * dj[q] : 0.f;
      } else {
        const int c = (r - 1) / 7;
        const int n = (r - 1) % 7;
        if (q == 0)
          val = (n == 6) ? dj[r] * dj[0] : 0.f;
        else
          val = dj[r] * lyj[(7 * (7 - c) + q - 1) * 7 + n] * dj[q];
      }
      (&o.x)[e] = val;
    }
    ((float4*)ob)[v4] = o;
  }
}

// ---------------------------------------------------------------------------
extern "C" void kernel_launch(void* const* d_in, const int* in_sizes, int n_in,
                              void* d_out, int out_size, void* d_ws, size_t ws_size,
                              hipStream_t stream) {
  const float* mat = (const float*)d_in[0];  // (1024,7,7)
  const float* tex = (const float*)d_in[1];  // (1024,15)
  const float* W = (const float*)d_in[2];    // (8192,1024)
  const float* b = (const float*)d_in[3];    // (8192,)
  float* out = (float*)d_out;                // (8192,57,57)

  char* ws = (char*)d_ws;
  _Float16* Xh = (_Float16*)(ws);                          // 1.5 MB
  _Float16* Wh = (_Float16*)(ws + (size_t)NPAD * HB * 2);  // 16.8 MB

  prep_kernel<<<NPAD + HM * HB / 4 / 256, 256, 0, stream>>>(
      mat, tex, (const float4*)W, Xh, (half4v*)Wh);
  fused_kernel<<<HM / FBM, 512, 0, stream>>>(Wh, Xh, b, out);
}

// Round 3
// 187.064 us; speedup vs baseline: 1.1453x; 1.1453x over previous
//
#include <hip/hip_runtime.h>

// Problem constants
#define HB 1024   // NUM_BASIC (GEMM K)
#define HM 8192   // NUM_MIXED (GEMM M)
#define NR 735    // 105*7 actual GEMM N
#define NPAD 768  // padded N
#define NOUT 57   // output is (HM, 57, 57)

// GEMM tiling: 64x128 block tile, BK=64 as two 32-wide K-panels
#define BM 64
#define BN 128
#define BK 64

typedef __attribute__((ext_vector_type(8))) _Float16 half8;
typedef __attribute__((ext_vector_type(4))) _Float16 half4v;
typedef __attribute__((ext_vector_type(4))) float floatx4;

// ---------------------------------------------------------------------------
// Kernel 1 (merged preps):
//  blocks [0, NPAD):        x2[r][h] = relu(te[h,t]*mat[h,n,m]) fp16,
//                           rows >= NR zeroed, K(h)-contiguous. r=(t*7+m)*7+n
//  blocks [NPAD, NPAD+8192): W fp32 -> fp16
// ---------------------------------------------------------------------------
__global__ __launch_bounds__(256) void prep_kernel(
    const float* __restrict__ mat, const float* __restrict__ tex,
    const float4* __restrict__ W,
    _Float16* __restrict__ Xh, half4v* __restrict__ Wh) {
  const int blk = blockIdx.x;
  if (blk < NPAD) {
    const int r = blk;
    const int n = r % 7;
    const int tm = r / 7;
    const int m = tm % 7;
    const int t = tm / 7;
#pragma unroll
    for (int i = 0; i < 4; ++i) {
      const int h = i * 256 + threadIdx.x;
      float v = 0.f;
      if (r < NR) {
        const float mv = mat[h * 49 + n * 7 + m];
        const float te = 1.f / (1.f + expf(-tex[h * 15 + t])) + 1.f;
        v = te * mv;
        v = v > 0.f ? v : 0.f;  // relu
      }
      Xh[r * HB + h] = (_Float16)v;
    }
  } else {
    const int idx = (blk - NPAD) * 256 + threadIdx.x;
    const float4 v = W[idx];
    half4v h;
    h.x = (_Float16)v.x;
    h.y = (_Float16)v.y;
    h.z = (_Float16)v.z;
    h.w = (_Float16)v.w;
    Wh[idx] = h;
  }
}

// ---------------------------------------------------------------------------
// Kernel 2: GEMM  Y[j][r] = relu( sum_h Wh[j][h]*Xh[r][h] + b[j] )
// M=8192, N=768, K=1024. Grid 768 = 3 blocks/CU. LDS 48KB (2x(8+16)KB).
// BK=64 as TWO 32-half K-panels per buffer: every LDS row stays 64B so the
// wave's ds_read_b128 fragment pattern is a fully-contiguous 1KB
// (conflict-free); 16 K-steps (half the barrier-drain events of BK=32),
// 16 MFMA/wave/step hides the prefetch latency.
// 4 waves, each 32x64 via 2x4x(2 ksub) grid of 16x16x32 f16 MFMAs.
// Bijective XCD swizzle: each XCD = 16 contiguous bm x all 6 bn ->
// A-slice 2MB + B 1.5MB L2-resident.
// ---------------------------------------------------------------------------
// Staging decomposition: 1KB chunks (16 rows x 32 halfs). Per buffer:
// A = 8 chunks (panel s = c>>2, row0 = (c&3)*16), wave w owns {2w, 2w+1};
// B = 16 chunks (panel s = c>>3, row0 = (c&7)*16), wave w owns {4w..4w+3}.
// Lane l covers chunk bytes l*16: row = row0 + (l>>2), k-off = (l&3)*8 halfs.
#define STAGE(pp, k0)                                                          \
  do {                                                                         \
    _Pragma("unroll")                                                          \
    for (int it_ = 0; it_ < 2; ++it_) {                                        \
      const int c_ = wave * 2 + it_;                                           \
      const int row_ = ((c_ & 3) * 16) + srow;                                 \
      const int kof_ = ((c_ >> 2) * 32) + skh;                                 \
      __builtin_amdgcn_global_load_lds(                                        \
          (const __attribute__((address_space(1))) void*)(                     \
              A + abase + (size_t)row_ * HB + (k0) + kof_),                    \
          (__attribute__((address_space(3))) void*)(&As[pp][c_ * 512 + lane * 8]), \
          16, 0, 0);                                                           \
    }                                                                          \
    _Pragma("unroll")                                                          \
    for (int it_ = 0; it_ < 4; ++it_) {                                        \
      const int c_ = wave * 4 + it_;                                           \
      const int row_ = ((c_ & 7) * 16) + srow;                                 \
      const int kof_ = ((c_ >> 3) * 32) + skh;                                 \
      __builtin_amdgcn_global_load_lds(                                        \
          (const __attribute__((address_space(1))) void*)(                     \
              B + bbase + (size_t)row_ * HB + (k0) + kof_),                    \
          (__attribute__((address_space(3))) void*)(&Bs[pp][c_ * 512 + lane * 8]), \
          16, 0, 0);                                                           \
    }                                                                          \
  } while (0)

__global__ __launch_bounds__(256) void gemm_kernel(
    const _Float16* __restrict__ A,  // Wh [8192][1024]
    const _Float16* __restrict__ B,  // Xh [768][1024]
    const float* __restrict__ bias,  // [8192]
    float* __restrict__ Y) {         // [8192][768]
  __shared__ __align__(16) _Float16 As[2][BM * BK];  // 2 x 8KB; [ksub][64][32]
  __shared__ __align__(16) _Float16 Bs[2][BN * BK];  // 2 x 16KB; [ksub][128][32]

  const int tid = threadIdx.x;
  const int lane = tid & 63;
  const int wave = tid >> 6;

  // bijective XCD swizzle over 768 blocks (768 = 8 XCD * 96)
  const int bid = blockIdx.x;
  const int wg = (bid & 7) * 96 + (bid >> 3);
  const int bn = wg % 6;
  const int bm = wg / 6;  // 0..127

  const int wm = (wave >> 1) * 32;  // wave sub-tile origin (M)
  const int wn = (wave & 1) * 64;   // wave sub-tile origin (N)

  floatx4 acc[2][4] = {};

  const int srow = lane >> 2;
  const int skh = (lane & 3) * 8;
  const size_t abase = (size_t)(bm * BM) * HB;
  const size_t bbase = (size_t)(bn * BN) * HB;

  const int mrow = lane & 15;
  const int quad = lane >> 4;

  STAGE(0, 0);
  __syncthreads();  // tile 0 visible

  int p = 0;
  for (int k0 = 0; k0 < HB; k0 += BK) {
    if (k0 + BK < HB) STAGE(p ^ 1, k0 + BK);  // prefetch issued pre-compute

    half8 af[2][2], bf[2][4];
#pragma unroll
    for (int s = 0; s < 2; ++s) {
#pragma unroll
      for (int i = 0; i < 2; ++i)
        af[s][i] =
            *(const half8*)(&As[p][s * 2048 + (wm + i * 16 + mrow) * 32 + quad * 8]);
#pragma unroll
      for (int j = 0; j < 4; ++j)
        bf[s][j] =
            *(const half8*)(&Bs[p][s * 4096 + (wn + j * 16 + mrow) * 32 + quad * 8]);
    }
#pragma unroll
    for (int s = 0; s < 2; ++s)
#pragma unroll
      for (int i = 0; i < 2; ++i)
#pragma unroll
        for (int j = 0; j < 4; ++j)
          acc[i][j] = __builtin_amdgcn_mfma_f32_16x16x32_f16(af[s][i], bf[s][j],
                                                             acc[i][j], 0, 0, 0);

    __syncthreads();  // drains prefetch vmcnt; all waves done with buf p
    p ^= 1;
  }

  // epilogue: bias + relu, D layout col=lane&15, row=(lane>>4)*4+reg
#pragma unroll
  for (int i = 0; i < 2; ++i) {
#pragma unroll
    for (int j = 0; j < 4; ++j) {
#pragma unroll
      for (int reg = 0; reg < 4; ++reg) {
        const int grow = bm * BM + wm + i * 16 + quad * 4 + reg;
        const int gcol = bn * BN + wn + j * 16 + mrow;
        float v = acc[i][j][reg] + bias[grow];
        v = v > 0.f ? v : 0.f;
        Y[(size_t)grow * NPAD + gcol] = v;
      }
    }
  }
}

// ---------------------------------------------------------------------------
// Kernel 3: epilogue, 4 j-rows per block (2048 blocks). mixed[r][q] (57x57):
//   r=0: 1 at q%7==0 (9 ones)
//   r>=1 (r-1 = c*7+n): q=0 -> (n==6); q>=1 -> y[j,n,7*(7-c)+q-1]
// where y[j,n,p] = Y[j][p*7+n]. d = rsqrt(max(1,rowsum)); out = d_r*mixed*d_q.
// 4 rows -> block out region = 4*3249 floats = 3249 float4 (16B-divisible),
// fully-coalesced vector stores.
// ---------------------------------------------------------------------------
__global__ __launch_bounds__(256) void epilogue_kernel(
    const float* __restrict__ Y, float* __restrict__ out) {
  const int j0 = blockIdx.x * 4;
  __shared__ float ly[4][NR];
  __shared__ float dd[4][NOUT];

#pragma unroll
  for (int jj = 0; jj < 4; ++jj)
    for (int i = threadIdx.x; i < NR; i += 256)
      ly[jj][i] = Y[(size_t)(j0 + jj) * NPAD + i];
  __syncthreads();

  if (threadIdx.x < 4 * NOUT) {
    const int jj = threadIdx.x / NOUT;
    const int r = threadIdx.x % NOUT;
    float s;
    if (r == 0) {
      s = 9.f;
    } else {
      const int c = (r - 1) / 7;
      const int n = (r - 1) % 7;
      const int base = 7 * (7 - c);  // starts[c]
      s = (n == 6) ? 1.f : 0.f;      // mixed[r][0]
      const float* lyj = ly[jj];
#pragma unroll
      for (int q = 0; q < 56; ++q) s += lyj[(base + q) * 7 + n];
    }
    s = s < 1.f ? 1.f : s;  // clip(.,1,None)
    dd[jj][r] = rsqrtf(s);
  }
  __syncthreads();

  // write: 3249 float4 per block, contiguous & 16B-aligned
  float4* ob = (float4*)(out + (size_t)j0 * (NOUT * NOUT));
  for (int v4 = threadIdx.x; v4 < NOUT * NOUT; v4 += 256) {
    float4 o;
#pragma unroll
    for (int e = 0; e < 4; ++e) {
      const int f = v4 * 4 + e;
      const int jj = f / (NOUT * NOUT);
      const int rem = f - jj * (NOUT * NOUT);
      const int r = rem / NOUT;
      const int q = rem - r * NOUT;
      const float* lyj = ly[jj];
      const float* dj = dd[jj];
      float val;
      if (r == 0) {
        val = (q % 7 == 0) ? dj[0] * dj[q] : 0.f;
      } else {
        const int c = (r - 1) / 7;
        const int n = (r - 1) % 7;
        if (q == 0)
          val = (n == 6) ? dj[r] * dj[0] : 0.f;
        else
          val = dj[r] * lyj[(7 * (7 - c) + q - 1) * 7 + n] * dj[q];
      }
      (&o.x)[e] = val;
    }
    ob[v4] = o;
  }
}

// ---------------------------------------------------------------------------
extern "C" void kernel_launch(void* const* d_in, const int* in_sizes, int n_in,
                              void* d_out, int out_size, void* d_ws, size_t ws_size,
                              hipStream_t stream) {
  const float* mat = (const float*)d_in[0];  // (1024,7,7)
  const float* tex = (const float*)d_in[1];  // (1024,15)
  const float* W = (const float*)d_in[2];    // (8192,1024)
  const float* b = (const float*)d_in[3];    // (8192,)
  float* out = (float*)d_out;                // (8192,57,57)

  char* ws = (char*)d_ws;
  _Float16* Xh = (_Float16*)(ws);                                  // 1.5 MB
  _Float16* Wh = (_Float16*)(ws + (size_t)NPAD * HB * 2);          // 16.8 MB
  float* Y = (float*)(ws + (size_t)NPAD * HB * 2 + (size_t)HM * HB * 2);  // 25.2 MB

  prep_kernel<<<NPAD + HM * HB / 4 / 256, 256, 0, stream>>>(
      mat, tex, (const float4*)W, Xh, (half4v*)Wh);
  gemm_kernel<<<HM / BM * (NPAD / BN), 256, 0, stream>>>(Wh, Xh, b, Y);
  epilogue_kernel<<<HM / 4, 256, 0, stream>>>(Y, out);
}